// Round 1
// baseline (227.736 us; speedup 1.0000x reference)
//
#include <hip/hip_runtime.h>
#include <math.h>

#define NJ 8          // j-axis chunks for chamfer pass
#define CB 256        // chamfer block size

// ---------------------------------------------------------------------------
// K1: p = Rz*Ry*Rx*(v + t), angles in degrees
// ---------------------------------------------------------------------------
__global__ void k_transform(const float* __restrict__ verts,
                            const float* __restrict__ trans,
                            const float* __restrict__ ax,
                            const float* __restrict__ ay,
                            const float* __restrict__ az,
                            float* __restrict__ out, int V)
{
    int i = blockIdx.x * blockDim.x + threadIdx.x;
    if (i >= V) return;
    const float D2R = 0.017453292519943295f;
    float tx = ax[0] * D2R, ty = ay[0] * D2R, tz = az[0] * D2R;
    float cx = cosf(tx), sx = sinf(tx);
    float cy = cosf(ty), sy = sinf(ty);
    float cz = cosf(tz), sz = sinf(tz);

    float x = verts[3*i+0] + trans[0];
    float y = verts[3*i+1] + trans[1];
    float z = verts[3*i+2] + trans[2];
    // p @ Rx^T
    float x1 = x;
    float y1 = cx*y - sx*z;
    float z1 = sx*y + cx*z;
    // p @ Ry^T
    float x2 =  cy*x1 + sy*z1;
    float y2 = y1;
    float z2 = -sy*x1 + cy*z1;
    // p @ Rz^T
    float x3 = cz*x2 - sz*y2;
    float y3 = sz*x2 + cz*y2;
    float z3 = z2;
    out[3*i+0] = x3; out[3*i+1] = y3; out[3*i+2] = z3;
}

// ---------------------------------------------------------------------------
// K2: sample points + normals on a mesh.
// ptsS = (x,y,z, x^2+y^2+z^2) ; nrm = (nx,ny,nz, 0)
// ---------------------------------------------------------------------------
__global__ void k_sample(const float* __restrict__ verts,
                         const int*   __restrict__ faces,
                         const int*   __restrict__ fidx,
                         const float* __restrict__ uv,
                         float4* __restrict__ ptsS,
                         float4* __restrict__ nrm, int N)
{
    int i = blockIdx.x * blockDim.x + threadIdx.x;
    if (i >= N) return;
    int f  = fidx[i];
    int i0 = faces[3*f+0], i1 = faces[3*f+1], i2 = faces[3*f+2];
    float v0x = verts[3*i0+0], v0y = verts[3*i0+1], v0z = verts[3*i0+2];
    float v1x = verts[3*i1+0], v1y = verts[3*i1+1], v1z = verts[3*i1+2];
    float v2x = verts[3*i2+0], v2y = verts[3*i2+1], v2z = verts[3*i2+2];

    float su = sqrtf(uv[2*i+0]);
    float vv = uv[2*i+1];
    float a = 1.0f - su;
    float b = su * (1.0f - vv);
    float c = su * vv;
    float px = a*v0x + b*v1x + c*v2x;
    float py = a*v0y + b*v1y + c*v2y;
    float pz = a*v0z + b*v1z + c*v2z;

    float e1x = v1x - v0x, e1y = v1y - v0y, e1z = v1z - v0z;
    float e2x = v2x - v0x, e2y = v2y - v0y, e2z = v2z - v0z;
    float nx = e1y*e2z - e1z*e2y;
    float ny = e1z*e2x - e1x*e2z;
    float nz = e1x*e2y - e1y*e2x;
    float nn = sqrtf(nx*nx + ny*ny + nz*nz) + 1e-8f;
    nx /= nn; ny /= nn; nz /= nn;

    ptsS[i] = make_float4(px, py, pz, px*px + py*py + pz*pz);
    nrm[i]  = make_float4(nx, ny, nz, 0.0f);
}

// ---------------------------------------------------------------------------
// K3: chamfer partial argmin: for each x_i, min over j in chunk blockIdx.y.
// d2 = |x|^2 + |y|^2 - 2 x.y  (same formula/order as reference).
// Strict < keeps first occurrence (numpy argmin tie-break).
// ---------------------------------------------------------------------------
__global__ void k_cham(const float4* __restrict__ X,
                       const float4* __restrict__ Y,
                       float* __restrict__ pval,
                       int*   __restrict__ pidx, int N)
{
    __shared__ float4 tile[(10000 + NJ - 1) / NJ + 16];
    int chunk = blockIdx.y;
    int j0 = (int)(((long long)N * chunk) / NJ);
    int j1 = (int)(((long long)N * (chunk + 1)) / NJ);
    int cnt = j1 - j0;
    for (int t = threadIdx.x; t < cnt; t += CB) tile[t] = Y[j0 + t];
    __syncthreads();

    int i = blockIdx.x * CB + threadIdx.x;
    if (i >= N) return;
    float4 x = X[i];
    float best = 3.4e38f;
    int   bi   = j0;
    for (int jj = 0; jj < cnt; ++jj) {
        float4 y = tile[jj];                       // broadcast, no conflicts
        float dot = x.x*y.x + x.y*y.y + x.z*y.z;
        float d   = x.w + y.w - 2.0f*dot;
        if (d < best) { best = d; bi = j0 + jj; }
    }
    pval[chunk*N + i] = best;
    pidx[chunk*N + i] = bi;
}

// ---------------------------------------------------------------------------
// K4: combine chunks + normal cosine terms + deterministic block reduction.
// loss = ( sum_i [cham_x + 1 - |nm.nf[ixy]|] + sum_j [cham_y + 1 - |nf.nm[iyx]|] ) / N
// ---------------------------------------------------------------------------
__global__ void k_loss(const float* __restrict__ pval_xy, const int* __restrict__ pidx_xy,
                       const float* __restrict__ pval_yx, const int* __restrict__ pidx_yx,
                       const float4* __restrict__ nm, const float4* __restrict__ nf,
                       float* __restrict__ out, int N)
{
    __shared__ float red[1024];
    float acc = 0.0f;
    for (int i = threadIdx.x; i < N; i += 1024) {
        // x -> y direction
        float best = pval_xy[i]; int bi = pidx_xy[i];
        for (int c = 1; c < NJ; ++c) {
            float v = pval_xy[c*N + i];
            if (v < best) { best = v; bi = pidx_xy[c*N + i]; }
        }
        float4 a = nm[i]; float4 b = nf[bi];
        float cosv = fabsf(a.x*b.x + a.y*b.y + a.z*b.z);
        acc += best + (1.0f - cosv);

        // y -> x direction
        best = pval_yx[i]; bi = pidx_yx[i];
        for (int c = 1; c < NJ; ++c) {
            float v = pval_yx[c*N + i];
            if (v < best) { best = v; bi = pidx_yx[c*N + i]; }
        }
        float4 a2 = nf[i]; float4 b2 = nm[bi];
        float cosv2 = fabsf(a2.x*b2.x + a2.y*b2.y + a2.z*b2.z);
        acc += best + (1.0f - cosv2);
    }
    red[threadIdx.x] = acc;
    __syncthreads();
    for (int s = 512; s > 0; s >>= 1) {
        if (threadIdx.x < s) red[threadIdx.x] += red[threadIdx.x + s];
        __syncthreads();
    }
    if (threadIdx.x == 0) out[0] = red[0] / (float)N;
}

// ---------------------------------------------------------------------------
extern "C" void kernel_launch(void* const* d_in, const int* in_sizes, int n_in,
                              void* d_out, int out_size, void* d_ws, size_t ws_size,
                              hipStream_t stream)
{
    const float* verts_mov = (const float*)d_in[0];
    const int*   faces_mov = (const int*)  d_in[1];
    const float* verts_fix = (const float*)d_in[2];
    const int*   faces_fix = (const int*)  d_in[3];
    const float* trans     = (const float*)d_in[4];
    const float* ax        = (const float*)d_in[5];
    const float* ay        = (const float*)d_in[6];
    const float* az        = (const float*)d_in[7];
    const int*   fidx_mov  = (const int*)  d_in[8];
    const float* uv_mov    = (const float*)d_in[9];
    const int*   fidx_fix  = (const int*)  d_in[10];
    const float* uv_fix    = (const float*)d_in[11];

    int V = in_sizes[0] / 3;
    int N = in_sizes[8];

    float* out = (float*)d_out;
    float* p   = out + 1;           // transformed verts region of output

    // workspace layout (floats)
    float*  ws      = (float*)d_ws;
    float4* ptsS_m  = (float4*)(ws + 0*4*N);
    float4* n_m     = (float4*)(ws + 1*4*N);
    float4* ptsS_f  = (float4*)(ws + 2*4*N);
    float4* n_f     = (float4*)(ws + 3*4*N);
    float*  pval_xy = ws + 16*N;
    int*    pidx_xy = (int*)(ws + 16*N + 1*NJ*N);
    float*  pval_yx = ws + 16*N + 2*NJ*N;
    int*    pidx_yx = (int*)(ws + 16*N + 3*NJ*N);

    k_transform<<<(V + 255)/256, 256, 0, stream>>>(verts_mov, trans, ax, ay, az, p, V);
    k_sample<<<(N + 255)/256, 256, 0, stream>>>(p,         faces_mov, fidx_mov, uv_mov, ptsS_m, n_m, N);
    k_sample<<<(N + 255)/256, 256, 0, stream>>>(verts_fix, faces_fix, fidx_fix, uv_fix, ptsS_f, n_f, N);

    dim3 gc((N + CB - 1)/CB, NJ);
    k_cham<<<gc, CB, 0, stream>>>(ptsS_m, ptsS_f, pval_xy, pidx_xy, N);
    k_cham<<<gc, CB, 0, stream>>>(ptsS_f, ptsS_m, pval_yx, pidx_yx, N);

    k_loss<<<1, 1024, 0, stream>>>(pval_xy, pidx_xy, pval_yx, pidx_yx, n_m, n_f, out, N);
}

// Round 2
// 122.426 us; speedup vs baseline: 1.8602x; 1.8602x over previous
//
#include <hip/hip_runtime.h>
#include <math.h>

#define NJ  32        // j-axis chunks per direction
#define CB  256       // chamfer block size (threads)
#define IPT 2         // x-points per thread

// ---------------------------------------------------------------------------
// K1: p = Rz*Ry*Rx*(v + t), angles in degrees
// ---------------------------------------------------------------------------
__global__ void k_transform(const float* __restrict__ verts,
                            const float* __restrict__ trans,
                            const float* __restrict__ ax,
                            const float* __restrict__ ay,
                            const float* __restrict__ az,
                            float* __restrict__ out, int V)
{
    int i = blockIdx.x * blockDim.x + threadIdx.x;
    if (i >= V) return;
    const float D2R = 0.017453292519943295f;
    float tx = ax[0] * D2R, ty = ay[0] * D2R, tz = az[0] * D2R;
    float cx = cosf(tx), sx = sinf(tx);
    float cy = cosf(ty), sy = sinf(ty);
    float cz = cosf(tz), sz = sinf(tz);

    float x = verts[3*i+0] + trans[0];
    float y = verts[3*i+1] + trans[1];
    float z = verts[3*i+2] + trans[2];
    float x1 = x;
    float y1 = cx*y - sx*z;
    float z1 = sx*y + cx*z;
    float x2 =  cy*x1 + sy*z1;
    float y2 = y1;
    float z2 = -sy*x1 + cy*z1;
    float x3 = cz*x2 - sz*y2;
    float y3 = sz*x2 + cz*y2;
    float z3 = z2;
    out[3*i+0] = x3; out[3*i+1] = y3; out[3*i+2] = z3;
}

// ---------------------------------------------------------------------------
// K2: sample points + normals, both meshes in one launch (blockIdx.y = which)
// ptsS = (x,y,z, |p|^2) ; nrm = (nx,ny,nz,0)
// ---------------------------------------------------------------------------
__global__ void k_sample2(const float* __restrict__ vertsA, const int* __restrict__ facesA,
                          const int* __restrict__ fidxA, const float* __restrict__ uvA,
                          float4* __restrict__ ptsA, float4* __restrict__ nrmA,
                          const float* __restrict__ vertsB, const int* __restrict__ facesB,
                          const int* __restrict__ fidxB, const float* __restrict__ uvB,
                          float4* __restrict__ ptsB, float4* __restrict__ nrmB, int N)
{
    int which = blockIdx.y;
    const float* verts = which ? vertsB : vertsA;
    const int*   faces = which ? facesB : facesA;
    const int*   fidx  = which ? fidxB  : fidxA;
    const float* uv    = which ? uvB    : uvA;
    float4* ptsS = which ? ptsB : ptsA;
    float4* nrm  = which ? nrmB : nrmA;

    int i = blockIdx.x * blockDim.x + threadIdx.x;
    if (i >= N) return;
    int f  = fidx[i];
    int i0 = faces[3*f+0], i1 = faces[3*f+1], i2 = faces[3*f+2];
    float v0x = verts[3*i0+0], v0y = verts[3*i0+1], v0z = verts[3*i0+2];
    float v1x = verts[3*i1+0], v1y = verts[3*i1+1], v1z = verts[3*i1+2];
    float v2x = verts[3*i2+0], v2y = verts[3*i2+1], v2z = verts[3*i2+2];

    float su = sqrtf(uv[2*i+0]);
    float vv = uv[2*i+1];
    float a = 1.0f - su;
    float b = su * (1.0f - vv);
    float c = su * vv;
    float px = a*v0x + b*v1x + c*v2x;
    float py = a*v0y + b*v1y + c*v2y;
    float pz = a*v0z + b*v1z + c*v2z;

    float e1x = v1x - v0x, e1y = v1y - v0y, e1z = v1z - v0z;
    float e2x = v2x - v0x, e2y = v2y - v0y, e2z = v2z - v0z;
    float nx = e1y*e2z - e1z*e2y;
    float ny = e1z*e2x - e1x*e2z;
    float nz = e1x*e2y - e1y*e2x;
    float nn = sqrtf(nx*nx + ny*ny + nz*nz) + 1e-8f;
    nx /= nn; ny /= nn; nz /= nn;

    ptsS[i] = make_float4(px, py, pz, px*px + py*py + pz*pz);
    nrm[i]  = make_float4(nx, ny, nz, 0.0f);
}

// ---------------------------------------------------------------------------
// K3: both chamfer directions in one launch.
// grid = (ceil(N/(CB*IPT)), NJ, 2).  dir=blockIdx.z: 0 = m->f, 1 = f->m.
// d2 = |x|^2 + |y|^2 - 2 x.y computed as fma chain with x prescaled by -2.
// Strict < keeps first occurrence (numpy argmin tie-break).
// ---------------------------------------------------------------------------
__global__ void k_cham2(const float4* __restrict__ Pm, const float4* __restrict__ Pf,
                        float* __restrict__ pval, int* __restrict__ pidx, int N)
{
    int dir = blockIdx.z;
    const float4* X = dir ? Pf : Pm;
    const float4* Y = dir ? Pm : Pf;
    float* pv = pval + (size_t)dir * NJ * N;
    int*   pi = pidx + (size_t)dir * NJ * N;

    __shared__ float4 tile[336];                 // >= ceil(10000/NJ)
    int chunk = blockIdx.y;
    int j0 = (int)(((long long)N * chunk) / NJ);
    int j1 = (int)(((long long)N * (chunk + 1)) / NJ);
    int cnt = j1 - j0;
    for (int t = threadIdx.x; t < cnt; t += CB) tile[t] = Y[j0 + t];
    __syncthreads();

    int ibase = blockIdx.x * CB * IPT + threadIdx.x;

    float xs[IPT][4];
    #pragma unroll
    for (int p = 0; p < IPT; ++p) {
        int i = ibase + p * CB;
        float4 x = (i < N) ? X[i] : make_float4(0.f, 0.f, 0.f, 0.f);
        xs[p][0] = -2.0f * x.x;
        xs[p][1] = -2.0f * x.y;
        xs[p][2] = -2.0f * x.z;
        xs[p][3] = x.w;
    }
    float best[IPT]; int bi[IPT];
    #pragma unroll
    for (int p = 0; p < IPT; ++p) { best[p] = 3.4e38f; bi[p] = j0; }

    #pragma unroll 4
    for (int jj = 0; jj < cnt; ++jj) {
        float4 y = tile[jj];                     // wave-broadcast read
        #pragma unroll
        for (int p = 0; p < IPT; ++p) {
            float d = fmaf(xs[p][0], y.x,
                      fmaf(xs[p][1], y.y,
                      fmaf(xs[p][2], y.z, xs[p][3] + y.w)));
            if (d < best[p]) { best[p] = d; bi[p] = j0 + jj; }
        }
    }
    #pragma unroll
    for (int p = 0; p < IPT; ++p) {
        int i = ibase + p * CB;
        if (i < N) { pv[(size_t)chunk*N + i] = best[p]; pi[(size_t)chunk*N + i] = bi[p]; }
    }
}

// ---------------------------------------------------------------------------
// K4: combine NJ partials per point, add normal-cosine term, block-reduce.
// grid = (ceil(N/256), 2); partial[dir*GX + bx] = block sum.
// ---------------------------------------------------------------------------
__global__ void k_combine(const float* __restrict__ pval, const int* __restrict__ pidx,
                          const float4* __restrict__ n_m, const float4* __restrict__ n_f,
                          float* __restrict__ partial, int N)
{
    int dir = blockIdx.y;
    const float* pv = pval + (size_t)dir * NJ * N;
    const int*   pi = pidx + (size_t)dir * NJ * N;

    int i = blockIdx.x * 256 + threadIdx.x;
    float term = 0.0f;
    if (i < N) {
        float best = pv[i]; int bi = pi[i];
        #pragma unroll
        for (int c = 1; c < NJ; ++c) {
            float v = pv[(size_t)c*N + i];
            if (v < best) { best = v; bi = pi[(size_t)c*N + i]; }
        }
        float4 a = dir ? n_f[i]  : n_m[i];
        float4 b = dir ? n_m[bi] : n_f[bi];
        term = best + 1.0f - fabsf(a.x*b.x + a.y*b.y + a.z*b.z);
    }
    __shared__ float red[256];
    red[threadIdx.x] = term;
    __syncthreads();
    for (int s = 128; s > 0; s >>= 1) {
        if (threadIdx.x < s) red[threadIdx.x] += red[threadIdx.x + s];
        __syncthreads();
    }
    if (threadIdx.x == 0) partial[dir * gridDim.x + blockIdx.x] = red[0];
}

// ---------------------------------------------------------------------------
// K5: final sum of per-block partials -> loss
// ---------------------------------------------------------------------------
__global__ void k_final(const float* __restrict__ partial, int nPart,
                        float* __restrict__ out, int N)
{
    __shared__ float red[256];
    float acc = 0.0f;
    for (int i = threadIdx.x; i < nPart; i += 256) acc += partial[i];
    red[threadIdx.x] = acc;
    __syncthreads();
    for (int s = 128; s > 0; s >>= 1) {
        if (threadIdx.x < s) red[threadIdx.x] += red[threadIdx.x + s];
        __syncthreads();
    }
    if (threadIdx.x == 0) out[0] = red[0] / (float)N;
}

// ---------------------------------------------------------------------------
extern "C" void kernel_launch(void* const* d_in, const int* in_sizes, int n_in,
                              void* d_out, int out_size, void* d_ws, size_t ws_size,
                              hipStream_t stream)
{
    const float* verts_mov = (const float*)d_in[0];
    const int*   faces_mov = (const int*)  d_in[1];
    const float* verts_fix = (const float*)d_in[2];
    const int*   faces_fix = (const int*)  d_in[3];
    const float* trans     = (const float*)d_in[4];
    const float* ax        = (const float*)d_in[5];
    const float* ay        = (const float*)d_in[6];
    const float* az        = (const float*)d_in[7];
    const int*   fidx_mov  = (const int*)  d_in[8];
    const float* uv_mov    = (const float*)d_in[9];
    const int*   fidx_fix  = (const int*)  d_in[10];
    const float* uv_fix    = (const float*)d_in[11];

    int V = in_sizes[0] / 3;
    int N = in_sizes[8];

    float* out = (float*)d_out;
    float* p   = out + 1;           // transformed verts region of output

    // workspace layout (floats)
    float*  ws      = (float*)d_ws;
    float4* ptsS_m  = (float4*)(ws + 0*4*N);
    float4* n_m     = (float4*)(ws + 1*4*N);
    float4* ptsS_f  = (float4*)(ws + 2*4*N);
    float4* n_f     = (float4*)(ws + 3*4*N);
    float*  pval    = ws + 16*N;                      // 2 * NJ * N floats
    int*    pidx    = (int*)(ws + 16*N + 2*NJ*N);     // 2 * NJ * N ints
    float*  partial = ws + 16*N + 4*NJ*N;             // small

    k_transform<<<(V + 255)/256, 256, 0, stream>>>(verts_mov, trans, ax, ay, az, p, V);

    dim3 gs((N + 255)/256, 2);
    k_sample2<<<gs, 256, 0, stream>>>(p, faces_mov, fidx_mov, uv_mov, ptsS_m, n_m,
                                      verts_fix, faces_fix, fidx_fix, uv_fix, ptsS_f, n_f, N);

    dim3 gc((N + CB*IPT - 1)/(CB*IPT), NJ, 2);
    k_cham2<<<gc, CB, 0, stream>>>(ptsS_m, ptsS_f, pval, pidx, N);

    int GX = (N + 255)/256;
    dim3 gk(GX, 2);
    k_combine<<<gk, 256, 0, stream>>>(pval, pidx, n_m, n_f, partial, N);

    k_final<<<1, 256, 0, stream>>>(partial, 2*GX, out, N);
}